// Round 2
// baseline (358.557 us; speedup 1.0000x reference)
//
#include <hip/hip_runtime.h>
#include <hip/hip_bf16.h>
#include <stdint.h>

#define N_NODES 100000
#define N_EDGES 600000
#define N_REL 4
#define N_HEADS 4
#define DIM 128
#define HEAD_DIM 32
#define NEG_SLOPE 0.2f

typedef unsigned int uint;
typedef unsigned short ushort;
typedef __attribute__((ext_vector_type(8))) short bf16x8;
typedef __attribute__((ext_vector_type(4))) float f32x4;

__device__ __forceinline__ float bf2f(ushort u) { return __uint_as_float(((uint)u) << 16); }
__device__ __forceinline__ float lo2f(uint u) { return __uint_as_float(u << 16); }
__device__ __forceinline__ float hi2f(uint u) { return __uint_as_float(u & 0xffff0000u); }
__device__ __forceinline__ ushort f2bf(float f) {
    uint u = __float_as_uint(f);
    uint r = (u + 0x7fffu + ((u >> 16) & 1u)) >> 16;   // round-to-nearest-even
    return (ushort)r;
}
__device__ __forceinline__ float lrelu(float v) { return v > 0.f ? v : NEG_SLOPE * v; }

// D0: on-device dtype-width detection (verified: floats fp32; ints detected at runtime).
__device__ __forceinline__ int bf16_plaus(ushort u) {
    int ex = (u >> 7) & 0xFF;
    return (ex >= 100 && ex <= 140) ? 1 : 0;
}
__global__ void k_detect(const ushort* __restrict__ x, const ushort* __restrict__ W,
                         const ushort* __restrict__ attn, const int* __restrict__ ei,
                         const int* __restrict__ et, int* __restrict__ flags) {
    __shared__ int cnt[5];
    int t = threadIdx.x;
    if (t < 5) cnt[t] = 0;
    __syncthreads();
    if (t < 128) {
        atomicAdd(&cnt[0], bf16_plaus(x[2 * t]));
        atomicAdd(&cnt[1], bf16_plaus(W[2 * t]));
        atomicAdd(&cnt[2], bf16_plaus(attn[2 * t]));
        atomicAdd(&cnt[3], (ei[2 * t + 1] != 0) ? 1 : 0);
        atomicAdd(&cnt[4], (et[2 * t + 1] != 0) ? 1 : 0);
    }
    __syncthreads();
    if (t == 0) {
        flags[0] = (cnt[0] < 64) ? 1 : 0;   // x is fp32
        flags[1] = (cnt[1] < 64) ? 1 : 0;   // W is fp32
        flags[2] = (cnt[2] < 64) ? 1 : 0;   // attn is fp32
        flags[3] = (cnt[3] < 8) ? 1 : 0;    // ei is int64
        flags[4] = (cnt[4] < 8) ? 1 : 0;    // et is int64
    }
}

// D1: canonicalize an integer tensor to int32 (takes low words if int64)
__global__ __launch_bounds__(256) void k_canon_i(
    const int* __restrict__ src, int* __restrict__ dst, int n,
    const int* __restrict__ flags, int flagIdx) {
    int i0 = (blockIdx.x * 256 + threadIdx.x) * 4;
    int i64f = flags[flagIdx];
#pragma unroll
    for (int j = 0; j < 4; j++) {
        int i = i0 + j;
        if (i < n) dst[i] = i64f ? src[2 * i] : src[i];
    }
}

// D2: x -> bf16 once
__global__ __launch_bounds__(256) void k_cvt_x(
    const void* __restrict__ xv, const int* __restrict__ flags,
    ushort* __restrict__ x_bf)
{
    int t = blockIdx.x * 256 + threadIdx.x;   // one per 8 elems
    if (t >= N_NODES * DIM / 8) return;
    if (flags[0]) {
        const float4* p = (const float4*)xv + (size_t)t * 2;
        float4 f0 = p[0], f1 = p[1];
        uint4 o;
        o.x = (uint)f2bf(f0.x) | ((uint)f2bf(f0.y) << 16);
        o.y = (uint)f2bf(f0.z) | ((uint)f2bf(f0.w) << 16);
        o.z = (uint)f2bf(f1.x) | ((uint)f2bf(f1.y) << 16);
        o.w = (uint)f2bf(f1.z) | ((uint)f2bf(f1.w) << 16);
        ((uint4*)x_bf)[t] = o;
    } else {
        ((uint4*)x_bf)[t] = ((const uint4*)xv)[t];
    }
}

// P0: one-time W transpose+convert into the exact LDS layout (bf16, padded to 136),
// and attn laid out as the 16x136 B-matrix. Runs ONCE (4 blocks).
__global__ __launch_bounds__(256) void k_prep_w(
    const void* __restrict__ Wv, const void* __restrict__ av,
    const int* __restrict__ flags,
    ushort* __restrict__ Wt_g, ushort* __restrict__ at_g)
{
    __shared__ ushort wt[128][136];
    const int r = blockIdx.x;
    const int tid = threadIdx.x;
    const int wf = flags[1], af = flags[2];

    if (wf) {
        const float4* Wg = (const float4*)((const float*)Wv + (size_t)r * DIM * DIM);
        for (int it = 0; it < 16; ++it) {
            int idx = tid + it * 256;              // 4096 float4 = 16384 floats
            int k = idx >> 5, n4 = (idx & 31) * 4;
            float4 v = Wg[idx];
            wt[n4 + 0][k] = f2bf(v.x);
            wt[n4 + 1][k] = f2bf(v.y);
            wt[n4 + 2][k] = f2bf(v.z);
            wt[n4 + 3][k] = f2bf(v.w);
        }
    } else {
        const ushort* Wg = (const ushort*)Wv + (size_t)r * DIM * DIM;
        for (int it = 0; it < 16; ++it) {
            int idx = tid + it * 256;
            int k = idx >> 5, n4 = (idx & 31) * 4;
            const ushort* p = Wg + (size_t)k * DIM + n4;
            wt[n4 + 0][k] = p[0];
            wt[n4 + 1][k] = p[1];
            wt[n4 + 2][k] = p[2];
            wt[n4 + 3][k] = p[3];
        }
    }
    __syncthreads();

    // write W^T rows coalesced as uint4: 128 rows * 17 chunks = 2176
    for (int it = 0; it < 9; ++it) {
        int idx = tid + it * 256;
        if (idx < 2176) {
            int row = idx / 17, c8 = (idx % 17) * 8;
            *(uint4*)(Wt_g + ((size_t)r * 128 + row) * 136 + c8) = *(const uint4*)&wt[row][c8];
        }
    }
    // attn B-matrix: 16 x 136 (rows n = sd*4+h for n<8, else zero; cols >=128 zero)
    for (int it = 0; it < 9; ++it) {
        int idx = tid + it * 256;                  // 2176 entries
        if (idx < 16 * 136) {
            int n = idx / 136, k = idx % 136;
            int h = n & 3, sd = (n >> 2) & 1;
            float v = 0.f;
            if (n < 8 && k < 128) {
                int d = k - h * 32;
                if (d >= 0 && d < 32) {
                    size_t ai = ((size_t)(r * N_HEADS + h)) * 64 + (size_t)sd * 32 + d;
                    v = af ? ((const float*)av)[ai] : bf2f(((const ushort*)av)[ai]);
                }
            }
            at_g[((size_t)r * 16 + n) * 136 + k] = f2bf(v);
        }
    }
}

// K1 (MFMA): x_rel[r] = x @ W[r]; scores via second MFMA pass on repacked x_rel.
// One (rowblock, rel) per block (grid 3128); W/attn pre-transposed by k_prep_w.
__global__ __launch_bounds__(256) void k_gemm_mfma(
    const ushort* __restrict__ x_bf, const ushort* __restrict__ Wt_g,
    const ushort* __restrict__ at_g,
    ushort* __restrict__ x_rel, float* __restrict__ sTab)
{
    __shared__ ushort wt[128][136];   // W^T [n][k]; reused as x_rel repack buffer (rp)
    __shared__ ushort at[16][136];    // attn as B matrix

    const int tid = threadIdx.x;
    const int wave = tid >> 6, lane = tid & 63;
    const int quad = lane >> 4, l16 = lane & 15;
    const int r = blockIdx.x & 3;            // consecutive blocks share x rows (L2)
    const int n0 = (blockIdx.x >> 2) * 128;

    // stage Wt (2176 uint4) + at (272 uint4) — linear, conflict-free
    {
        const uint4* src  = (const uint4*)(Wt_g + (size_t)r * 128 * 136);
        const uint4* srcA = (const uint4*)(at_g + (size_t)r * 16 * 136);
        uint4* dstL = (uint4*)&wt[0][0];
        uint4* dstA = (uint4*)&at[0][0];
#pragma unroll
        for (int it = 0; it < 10; ++it) {
            int idx = tid + it * 256;
            if (idx < 2176) dstL[idx] = src[idx];
            else if (idx < 2448) dstA[idx - 2176] = srcA[idx - 2176];
        }
    }

    const int rowA0 = n0 + wave * 32 + l16;
    const int rowA1 = rowA0 + 16;
    const size_t rA0 = (size_t)min(rowA0, N_NODES - 1) * DIM;
    const size_t rA1 = (size_t)min(rowA1, N_NODES - 1) * DIM;

    __syncthreads();

    f32x4 acc[2][8];
#pragma unroll
    for (int rt = 0; rt < 2; ++rt)
#pragma unroll
        for (int ct = 0; ct < 8; ++ct) acc[rt][ct] = (f32x4){0.f, 0.f, 0.f, 0.f};

#pragma unroll
    for (int q = 0; q < 4; ++q) {
        const int kb = q * 32 + quad * 8;
        bf16x8 a0 = *(const bf16x8*)(x_bf + rA0 + kb);
        bf16x8 a1 = *(const bf16x8*)(x_bf + rA1 + kb);
#pragma unroll
        for (int ct = 0; ct < 8; ++ct) {
            bf16x8 b = *(const bf16x8*)&wt[ct * 16 + l16][kb];
            acc[0][ct] = __builtin_amdgcn_mfma_f32_16x16x32_bf16(a0, b, acc[0][ct], 0, 0, 0);
            acc[1][ct] = __builtin_amdgcn_mfma_f32_16x16x32_bf16(a1, b, acc[1][ct], 0, 0, 0);
        }
    }
    __syncthreads();

    {
        ushort* rp = &wt[0][0];
#pragma unroll
        for (int rt = 0; rt < 2; ++rt) {
            int rowb = wave * 32 + rt * 16 + quad * 4;
#pragma unroll
            for (int ct = 0; ct < 8; ++ct) {
                int col = ct * 16 + l16;
#pragma unroll
                for (int reg = 0; reg < 4; ++reg)
                    rp[(rowb + reg) * 136 + col] = f2bf(acc[rt][ct][reg]);
            }
        }
    }
    __syncthreads();

    // scores = x_rel · attn  (A = rp rows, B = at)
    {
        const ushort* rp = &wt[0][0];
        f32x4 sacc[2];
        sacc[0] = (f32x4){0.f, 0.f, 0.f, 0.f};
        sacc[1] = (f32x4){0.f, 0.f, 0.f, 0.f};
#pragma unroll
        for (int q = 0; q < 4; ++q) {
            const int kb = q * 32 + quad * 8;
            bf16x8 a0 = *(const bf16x8*)(rp + (wave * 32 + l16) * 136 + kb);
            bf16x8 a1 = *(const bf16x8*)(rp + (wave * 32 + 16 + l16) * 136 + kb);
            bf16x8 bat = *(const bf16x8*)&at[l16][kb];
            sacc[0] = __builtin_amdgcn_mfma_f32_16x16x32_bf16(a0, bat, sacc[0], 0, 0, 0);
            sacc[1] = __builtin_amdgcn_mfma_f32_16x16x32_bf16(a1, bat, sacc[1], 0, 0, 0);
        }
        if (l16 < 8) {
#pragma unroll
            for (int rt = 0; rt < 2; ++rt) {
#pragma unroll
                for (int reg = 0; reg < 4; ++reg) {
                    int node = n0 + wave * 32 + rt * 16 + quad * 4 + reg;
                    if (node < N_NODES)
                        sTab[((size_t)r * N_NODES + node) * 8 + l16] = sacc[rt][reg];
                }
            }
        }
    }

    {
        const ushort* rp = &wt[0][0];
        const size_t rbase = (size_t)r * N_NODES * DIM;
#pragma unroll
        for (int p = 0; p < 8; ++p) {
            int row = p * 16 + (tid >> 4);
            int chunk = tid & 15;
            int node = n0 + row;
            if (node < N_NODES) {
                uint4 v = *(const uint4*)(rp + row * 136 + chunk * 8);
                *(uint4*)(x_rel + rbase + (size_t)node * DIM + chunk * 8) = v;
            }
        }
    }
}

// C1: in-degree histogram
__global__ __launch_bounds__(256) void k_hist(
    const int* __restrict__ ei, uint* __restrict__ deg)
{
    int e = blockIdx.x * 256 + threadIdx.x;
    if (e >= N_EDGES) return;
    atomicAdd(&deg[ei[N_EDGES + e]], 1u);
}

// C2a: per-block exclusive scan + block sums
__global__ __launch_bounds__(256) void k_scan1(
    const uint* __restrict__ deg, uint* __restrict__ excl, uint* __restrict__ bsum)
{
    __shared__ uint tmp[256];
    int i = blockIdx.x * 256 + threadIdx.x;
    uint v = (i < N_NODES) ? deg[i] : 0u;
    tmp[threadIdx.x] = v;
    __syncthreads();
    for (int off = 1; off < 256; off <<= 1) {
        uint t = (threadIdx.x >= off) ? tmp[threadIdx.x - off] : 0u;
        __syncthreads();
        tmp[threadIdx.x] += t;
        __syncthreads();
    }
    if (i < N_NODES) excl[i] = tmp[threadIdx.x] - v;
    if (threadIdx.x == 255) bsum[blockIdx.x] = tmp[255];
}

// C2b: scan block sums (nblocks <= 512)
__global__ __launch_bounds__(512) void k_scan2(uint* __restrict__ bsum, int nblocks)
{
    __shared__ uint tmp[512];
    int t = threadIdx.x;
    uint v = (t < nblocks) ? bsum[t] : 0u;
    tmp[t] = v;
    __syncthreads();
    for (int off = 1; off < 512; off <<= 1) {
        uint tt = (t >= off) ? tmp[t - off] : 0u;
        __syncthreads();
        tmp[t] += tt;
        __syncthreads();
    }
    if (t < nblocks) bsum[t] = tmp[t] - v;   // exclusive
}

// C2c: start = excl + block offset; cursor = start
__global__ __launch_bounds__(256) void k_scan3(
    const uint* __restrict__ excl, const uint* __restrict__ bsum,
    uint* __restrict__ start, uint* __restrict__ cursor)
{
    int i = blockIdx.x * 256 + threadIdx.x;
    if (i >= N_NODES) return;
    uint s = excl[i] + bsum[blockIdx.x];
    start[i] = s;
    cursor[i] = s;
}

// C3: fill CSR: packed (src | rel<<27)
__global__ __launch_bounds__(256) void k_fill(
    const int* __restrict__ ei, const int* __restrict__ et,
    uint* __restrict__ cursor, uint* __restrict__ csrPack)
{
    int e = blockIdx.x * 256 + threadIdx.x;
    if (e >= N_EDGES) return;
    int s = ei[e];
    int d = ei[N_EDGES + e];
    int r = et[e];
    uint pos = atomicAdd(&cursor[d], 1u);
    csrPack[pos] = (uint)s | ((uint)r << 27);
}

// W1: per-edge normalized softmax weights, ONE THREAD PER DST (removes the
// 64x wave-redundant shfl-broadcast softmax that was 74% VALUBusy in the
// fused gather). Two serial passes over the dst's CSR range; all state in
// registers with compile-time indices (no scratch). Handles ANY degree.
__global__ __launch_bounds__(256) void k_weights(
    const uint* __restrict__ start, const uint* __restrict__ deg,
    const uint* __restrict__ csrPack, const float* __restrict__ sTab,
    float* __restrict__ wTab)
{
    int d = blockIdx.x * 256 + threadIdx.x;
    if (d >= N_NODES) return;
    const uint st = start[d];
    const uint dg = deg[d];
    if (dg == 0u) return;

    // dst-part of the logit for each rel (4 floats per rel, one per head)
    float4 bp0 = *(const float4*)(sTab + ((size_t)0 * N_NODES + d) * 8 + 4);
    float4 bp1 = *(const float4*)(sTab + ((size_t)1 * N_NODES + d) * 8 + 4);
    float4 bp2 = *(const float4*)(sTab + ((size_t)2 * N_NODES + d) * 8 + 4);
    float4 bp3 = *(const float4*)(sTab + ((size_t)3 * N_NODES + d) * 8 + 4);

    float4 dn0 = {0.f, 0.f, 0.f, 0.f}, dn1 = dn0, dn2 = dn0, dn3 = dn0;

    // pass 1: per-(rel, head) denominators
    for (uint e = 0; e < dg; ++e) {
        uint pk = csrPack[st + e];
        int re = (int)(pk >> 27);
        uint s = pk & 0x07FFFFFFu;
        float4 a = *(const float4*)(sTab + ((size_t)re * N_NODES + s) * 8);
        float4 bp = (re < 2) ? (re == 0 ? bp0 : bp1) : (re == 2 ? bp2 : bp3);
        float y0 = __expf(lrelu(a.x + bp.x));
        float y1 = __expf(lrelu(a.y + bp.y));
        float y2 = __expf(lrelu(a.z + bp.z));
        float y3 = __expf(lrelu(a.w + bp.w));
        dn0.x += (re == 0) ? y0 : 0.f;  dn0.y += (re == 0) ? y1 : 0.f;
        dn0.z += (re == 0) ? y2 : 0.f;  dn0.w += (re == 0) ? y3 : 0.f;
        dn1.x += (re == 1) ? y0 : 0.f;  dn1.y += (re == 1) ? y1 : 0.f;
        dn1.z += (re == 1) ? y2 : 0.f;  dn1.w += (re == 1) ? y3 : 0.f;
        dn2.x += (re == 2) ? y0 : 0.f;  dn2.y += (re == 2) ? y1 : 0.f;
        dn2.z += (re == 2) ? y2 : 0.f;  dn2.w += (re == 2) ? y3 : 0.f;
        dn3.x += (re == 3) ? y0 : 0.f;  dn3.y += (re == 3) ? y1 : 0.f;
        dn3.z += (re == 3) ? y2 : 0.f;  dn3.w += (re == 3) ? y3 : 0.f;
    }
    float4 rd0, rd1, rd2, rd3;   // unused rels: inf, never read
    rd0.x = 1.f / dn0.x; rd0.y = 1.f / dn0.y; rd0.z = 1.f / dn0.z; rd0.w = 1.f / dn0.w;
    rd1.x = 1.f / dn1.x; rd1.y = 1.f / dn1.y; rd1.z = 1.f / dn1.z; rd1.w = 1.f / dn1.w;
    rd2.x = 1.f / dn2.x; rd2.y = 1.f / dn2.y; rd2.z = 1.f / dn2.z; rd2.w = 1.f / dn2.w;
    rd3.x = 1.f / dn3.x; rd3.y = 1.f / dn3.y; rd3.z = 1.f / dn3.z; rd3.w = 1.f / dn3.w;

    // pass 2: recompute exp (L1-hot reload, identical FP result), normalize, store
    for (uint e = 0; e < dg; ++e) {
        uint pk = csrPack[st + e];
        int re = (int)(pk >> 27);
        uint s = pk & 0x07FFFFFFu;
        float4 a = *(const float4*)(sTab + ((size_t)re * N_NODES + s) * 8);
        float4 bp = (re < 2) ? (re == 0 ? bp0 : bp1) : (re == 2 ? bp2 : bp3);
        float4 rs = (re < 2) ? (re == 0 ? rd0 : rd1) : (re == 2 ? rd2 : rd3);
        float4 w;
        w.x = __expf(lrelu(a.x + bp.x)) * rs.x;
        w.y = __expf(lrelu(a.y + bp.y)) * rs.y;
        w.z = __expf(lrelu(a.z + bp.z)) * rs.z;
        w.w = __expf(lrelu(a.w + bp.w)) * rs.w;
        ((float4*)wTab)[st + e] = w;
    }
}

// K4: pure weighted gather. One wave per dst, all degrees, no shfl/exp/softmax.
// Per edge: uniform pk load, head-broadcast weight load, 256B x_rel row, 2 FMA.
__global__ __launch_bounds__(256) void k_gather2(
    const uint* __restrict__ start, const uint* __restrict__ deg,
    const uint* __restrict__ csrPack, const float* __restrict__ wTab,
    const uint* __restrict__ x_rel_u, float* __restrict__ out)
{
    const int wv = threadIdx.x >> 6;
    const int dst = blockIdx.x * 4 + wv;
    if (dst >= N_NODES) return;
    const int lane = threadIdx.x & 63;
    const int h = lane >> 4;

    const uint st = start[dst];
    const uint dg = deg[dst];
    float a0 = 0.f, a1 = 0.f;

    for (uint e = 0; e < dg; ++e) {
        uint pk = csrPack[st + e];
        float mw = wTab[(size_t)(st + e) * 4 + h];
        uint s = pk & 0x07FFFFFFu;
        uint re = pk >> 27;
        uint u = x_rel_u[((size_t)re * N_NODES + s) * 64 + lane];
        a0 = fmaf(mw, lo2f(u), a0);
        a1 = fmaf(mw, hi2f(u), a1);
    }
    float2 o; o.x = a0; o.y = a1;
    *(float2*)(out + (size_t)dst * DIM + lane * 2) = o;
}

extern "C" void kernel_launch(void* const* d_in, const int* in_sizes, int n_in,
                              void* d_out, int out_size, void* d_ws, size_t ws_size,
                              hipStream_t stream) {
    const void* x    = d_in[0];
    const int*  ei   = (const int*)d_in[1];
    const int*  et   = (const int*)d_in[2];
    const void* W    = d_in[3];
    const void* attn = d_in[4];
    float* out = (float*)d_out;

    char* ws = (char*)d_ws;
    int*    flags   = (int*)(ws + 0);               // 256 B
    int*    eic     = (int*)(ws + 256);             // 4,800,000
    int*    etc_    = (int*)(ws + 4800256);         // 2,400,000
    float*  sTab    = (float*)(ws + 7200256);       // 12,800,000
    ushort* x_rel   = (ushort*)(ws + 20000256);     // 102,400,000
    uint*   deg     = (uint*)(ws + 122400256);      // 400,000
    uint*   excl    = (uint*)(ws + 122800256);      // 400,000
    uint*   bsum    = (uint*)(ws + 123200256);      // 2,048
    uint*   startA  = (uint*)(ws + 123202304);      // 400,000
    uint*   cursor  = (uint*)(ws + 123602304);      // 400,000
    uint*   csrPack = (uint*)(ws + 124002304);      // 2,400,000
    ushort* x_bf    = (ushort*)(ws + 126402304);    // 25,600,000
    // total 152,002,304 B
    // Aliases (stream-ordered disjoint lifetimes):
    //  Wt_g/at_g alias excl/startA (dead until k_scan1/k_scan3 write them);
    //  wTab aliases x_bf (x_bf last read by k_gemm_mfma; k_weights runs after).
    ushort* Wt_g    = (ushort*)(ws + 122800256);    // 139,264 (aliases excl)
    ushort* at_g    = (ushort*)(ws + 123202304);    // 17,408  (aliases startA)
    float*  wTab    = (float*)(ws + 126402304);     // 9,600,000 (aliases x_bf)

    const int NBLK = (N_NODES + 255) / 256;   // 391

    hipMemsetAsync(deg, 0, 400000, stream);

    k_detect<<<1, 256, 0, stream>>>((const ushort*)x, (const ushort*)W,
                                    (const ushort*)attn, ei, et, flags);
    k_prep_w<<<N_REL, 256, 0, stream>>>(W, attn, flags, Wt_g, at_g);
    k_canon_i<<<(2 * N_EDGES / 4 + 255) / 256, 256, 0, stream>>>(ei, eic, 2 * N_EDGES, flags, 3);
    k_canon_i<<<(N_EDGES / 4 + 255) / 256, 256, 0, stream>>>(et, etc_, N_EDGES, flags, 4);
    k_cvt_x<<<(N_NODES * DIM / 8 + 255) / 256, 256, 0, stream>>>(x, flags, x_bf);

    k_gemm_mfma<<<((N_NODES + 127) / 128) * N_REL, 256, 0, stream>>>(x_bf, Wt_g, at_g,
                                                                     x_rel, sTab);

    k_hist<<<(N_EDGES + 255) / 256, 256, 0, stream>>>(eic, deg);
    k_scan1<<<NBLK, 256, 0, stream>>>(deg, excl, bsum);
    k_scan2<<<1, 512, 0, stream>>>(bsum, NBLK);
    k_scan3<<<NBLK, 256, 0, stream>>>(excl, bsum, startA, cursor);
    k_fill<<<(N_EDGES + 255) / 256, 256, 0, stream>>>(eic, etc_, cursor, csrPack);
    k_weights<<<NBLK, 256, 0, stream>>>(startA, deg, csrPack, sTab, wTab);
    k_gather2<<<(N_NODES + 3) / 4, 256, 0, stream>>>(startA, deg, csrPack, wTab,
                                                     (const uint*)x_rel, out);
}

// Round 3
// 327.635 us; speedup vs baseline: 1.0944x; 1.0944x over previous
//
#include <hip/hip_runtime.h>
#include <hip/hip_bf16.h>
#include <stdint.h>

#define N_NODES 100000
#define N_EDGES 600000
#define N_REL 4
#define N_HEADS 4
#define DIM 128
#define HEAD_DIM 32
#define NEG_SLOPE 0.2f

typedef unsigned int uint;
typedef unsigned short ushort;
typedef __attribute__((ext_vector_type(8))) short bf16x8;
typedef __attribute__((ext_vector_type(4))) float f32x4;

__device__ __forceinline__ float bf2f(ushort u) { return __uint_as_float(((uint)u) << 16); }
__device__ __forceinline__ float lo2f(uint u) { return __uint_as_float(u << 16); }
__device__ __forceinline__ float hi2f(uint u) { return __uint_as_float(u & 0xffff0000u); }
__device__ __forceinline__ ushort f2bf(float f) {
    uint u = __float_as_uint(f);
    uint r = (u + 0x7fffu + ((u >> 16) & 1u)) >> 16;   // round-to-nearest-even
    return (ushort)r;
}
__device__ __forceinline__ float lrelu(float v) { return v > 0.f ? v : NEG_SLOPE * v; }

// D0: on-device dtype-width detection (verified: floats fp32; ints detected at runtime).
__device__ __forceinline__ int bf16_plaus(ushort u) {
    int ex = (u >> 7) & 0xFF;
    return (ex >= 100 && ex <= 140) ? 1 : 0;
}
__global__ void k_detect(const ushort* __restrict__ x, const ushort* __restrict__ W,
                         const ushort* __restrict__ attn, const int* __restrict__ ei,
                         const int* __restrict__ et, int* __restrict__ flags) {
    __shared__ int cnt[5];
    int t = threadIdx.x;
    if (t < 5) cnt[t] = 0;
    __syncthreads();
    if (t < 128) {
        atomicAdd(&cnt[0], bf16_plaus(x[2 * t]));
        atomicAdd(&cnt[1], bf16_plaus(W[2 * t]));
        atomicAdd(&cnt[2], bf16_plaus(attn[2 * t]));
        atomicAdd(&cnt[3], (ei[2 * t + 1] != 0) ? 1 : 0);
        atomicAdd(&cnt[4], (et[2 * t + 1] != 0) ? 1 : 0);
    }
    __syncthreads();
    if (t == 0) {
        flags[0] = (cnt[0] < 64) ? 1 : 0;   // x is fp32
        flags[1] = (cnt[1] < 64) ? 1 : 0;   // W is fp32
        flags[2] = (cnt[2] < 64) ? 1 : 0;   // attn is fp32
        flags[3] = (cnt[3] < 8) ? 1 : 0;    // ei is int64
        flags[4] = (cnt[4] < 8) ? 1 : 0;    // et is int64
    }
}

// D1: canonicalize an integer tensor to int32 (takes low words if int64)
__global__ __launch_bounds__(256) void k_canon_i(
    const int* __restrict__ src, int* __restrict__ dst, int n,
    const int* __restrict__ flags, int flagIdx) {
    int i0 = (blockIdx.x * 256 + threadIdx.x) * 4;
    int i64f = flags[flagIdx];
#pragma unroll
    for (int j = 0; j < 4; j++) {
        int i = i0 + j;
        if (i < n) dst[i] = i64f ? src[2 * i] : src[i];
    }
}

// D2: x -> bf16 once
__global__ __launch_bounds__(256) void k_cvt_x(
    const void* __restrict__ xv, const int* __restrict__ flags,
    ushort* __restrict__ x_bf)
{
    int t = blockIdx.x * 256 + threadIdx.x;   // one per 8 elems
    if (t >= N_NODES * DIM / 8) return;
    if (flags[0]) {
        const float4* p = (const float4*)xv + (size_t)t * 2;
        float4 f0 = p[0], f1 = p[1];
        uint4 o;
        o.x = (uint)f2bf(f0.x) | ((uint)f2bf(f0.y) << 16);
        o.y = (uint)f2bf(f0.z) | ((uint)f2bf(f0.w) << 16);
        o.z = (uint)f2bf(f1.x) | ((uint)f2bf(f1.y) << 16);
        o.w = (uint)f2bf(f1.z) | ((uint)f2bf(f1.w) << 16);
        ((uint4*)x_bf)[t] = o;
    } else {
        ((uint4*)x_bf)[t] = ((const uint4*)xv)[t];
    }
}

// P0: one-time W transpose+convert into the exact LDS layout (bf16, padded to 136),
// and attn laid out as the 16x136 B-matrix. Runs ONCE (4 blocks).
__global__ __launch_bounds__(256) void k_prep_w(
    const void* __restrict__ Wv, const void* __restrict__ av,
    const int* __restrict__ flags,
    ushort* __restrict__ Wt_g, ushort* __restrict__ at_g)
{
    __shared__ ushort wt[128][136];
    const int r = blockIdx.x;
    const int tid = threadIdx.x;
    const int wf = flags[1], af = flags[2];

    if (wf) {
        const float4* Wg = (const float4*)((const float*)Wv + (size_t)r * DIM * DIM);
        for (int it = 0; it < 16; ++it) {
            int idx = tid + it * 256;              // 4096 float4 = 16384 floats
            int k = idx >> 5, n4 = (idx & 31) * 4;
            float4 v = Wg[idx];
            wt[n4 + 0][k] = f2bf(v.x);
            wt[n4 + 1][k] = f2bf(v.y);
            wt[n4 + 2][k] = f2bf(v.z);
            wt[n4 + 3][k] = f2bf(v.w);
        }
    } else {
        const ushort* Wg = (const ushort*)Wv + (size_t)r * DIM * DIM;
        for (int it = 0; it < 16; ++it) {
            int idx = tid + it * 256;
            int k = idx >> 5, n4 = (idx & 31) * 4;
            const ushort* p = Wg + (size_t)k * DIM + n4;
            wt[n4 + 0][k] = p[0];
            wt[n4 + 1][k] = p[1];
            wt[n4 + 2][k] = p[2];
            wt[n4 + 3][k] = p[3];
        }
    }
    __syncthreads();

    // write W^T rows coalesced as uint4: 128 rows * 17 chunks = 2176
    for (int it = 0; it < 9; ++it) {
        int idx = tid + it * 256;
        if (idx < 2176) {
            int row = idx / 17, c8 = (idx % 17) * 8;
            *(uint4*)(Wt_g + ((size_t)r * 128 + row) * 136 + c8) = *(const uint4*)&wt[row][c8];
        }
    }
    // attn B-matrix: 16 x 136 (rows n = sd*4+h for n<8, else zero; cols >=128 zero)
    for (int it = 0; it < 9; ++it) {
        int idx = tid + it * 256;                  // 2176 entries
        if (idx < 16 * 136) {
            int n = idx / 136, k = idx % 136;
            int h = n & 3, sd = (n >> 2) & 1;
            float v = 0.f;
            if (n < 8 && k < 128) {
                int d = k - h * 32;
                if (d >= 0 && d < 32) {
                    size_t ai = ((size_t)(r * N_HEADS + h)) * 64 + (size_t)sd * 32 + d;
                    v = af ? ((const float*)av)[ai] : bf2f(((const ushort*)av)[ai]);
                }
            }
            at_g[((size_t)r * 16 + n) * 136 + k] = f2bf(v);
        }
    }
}

// K1 (MFMA): x_rel[r] = x @ W[r]; scores via second MFMA pass on repacked x_rel.
// One (rowblock, rel) per block (grid 3128); W/attn pre-transposed by k_prep_w.
__global__ __launch_bounds__(256) void k_gemm_mfma(
    const ushort* __restrict__ x_bf, const ushort* __restrict__ Wt_g,
    const ushort* __restrict__ at_g,
    ushort* __restrict__ x_rel, float* __restrict__ sTab)
{
    __shared__ ushort wt[128][136];   // W^T [n][k]; reused as x_rel repack buffer (rp)
    __shared__ ushort at[16][136];    // attn as B matrix

    const int tid = threadIdx.x;
    const int wave = tid >> 6, lane = tid & 63;
    const int quad = lane >> 4, l16 = lane & 15;
    const int r = blockIdx.x & 3;            // consecutive blocks share x rows (L2)
    const int n0 = (blockIdx.x >> 2) * 128;

    // stage Wt (2176 uint4) + at (272 uint4) — linear, conflict-free
    {
        const uint4* src  = (const uint4*)(Wt_g + (size_t)r * 128 * 136);
        const uint4* srcA = (const uint4*)(at_g + (size_t)r * 16 * 136);
        uint4* dstL = (uint4*)&wt[0][0];
        uint4* dstA = (uint4*)&at[0][0];
#pragma unroll
        for (int it = 0; it < 10; ++it) {
            int idx = tid + it * 256;
            if (idx < 2176) dstL[idx] = src[idx];
            else if (idx < 2448) dstA[idx - 2176] = srcA[idx - 2176];
        }
    }

    const int rowA0 = n0 + wave * 32 + l16;
    const int rowA1 = rowA0 + 16;
    const size_t rA0 = (size_t)min(rowA0, N_NODES - 1) * DIM;
    const size_t rA1 = (size_t)min(rowA1, N_NODES - 1) * DIM;

    __syncthreads();

    f32x4 acc[2][8];
#pragma unroll
    for (int rt = 0; rt < 2; ++rt)
#pragma unroll
        for (int ct = 0; ct < 8; ++ct) acc[rt][ct] = (f32x4){0.f, 0.f, 0.f, 0.f};

#pragma unroll
    for (int q = 0; q < 4; ++q) {
        const int kb = q * 32 + quad * 8;
        bf16x8 a0 = *(const bf16x8*)(x_bf + rA0 + kb);
        bf16x8 a1 = *(const bf16x8*)(x_bf + rA1 + kb);
#pragma unroll
        for (int ct = 0; ct < 8; ++ct) {
            bf16x8 b = *(const bf16x8*)&wt[ct * 16 + l16][kb];
            acc[0][ct] = __builtin_amdgcn_mfma_f32_16x16x32_bf16(a0, b, acc[0][ct], 0, 0, 0);
            acc[1][ct] = __builtin_amdgcn_mfma_f32_16x16x32_bf16(a1, b, acc[1][ct], 0, 0, 0);
        }
    }
    __syncthreads();

    {
        ushort* rp = &wt[0][0];
#pragma unroll
        for (int rt = 0; rt < 2; ++rt) {
            int rowb = wave * 32 + rt * 16 + quad * 4;
#pragma unroll
            for (int ct = 0; ct < 8; ++ct) {
                int col = ct * 16 + l16;
#pragma unroll
                for (int reg = 0; reg < 4; ++reg)
                    rp[(rowb + reg) * 136 + col] = f2bf(acc[rt][ct][reg]);
            }
        }
    }
    __syncthreads();

    // scores = x_rel · attn  (A = rp rows, B = at)
    {
        const ushort* rp = &wt[0][0];
        f32x4 sacc[2];
        sacc[0] = (f32x4){0.f, 0.f, 0.f, 0.f};
        sacc[1] = (f32x4){0.f, 0.f, 0.f, 0.f};
#pragma unroll
        for (int q = 0; q < 4; ++q) {
            const int kb = q * 32 + quad * 8;
            bf16x8 a0 = *(const bf16x8*)(rp + (wave * 32 + l16) * 136 + kb);
            bf16x8 a1 = *(const bf16x8*)(rp + (wave * 32 + 16 + l16) * 136 + kb);
            bf16x8 bat = *(const bf16x8*)&at[l16][kb];
            sacc[0] = __builtin_amdgcn_mfma_f32_16x16x32_bf16(a0, bat, sacc[0], 0, 0, 0);
            sacc[1] = __builtin_amdgcn_mfma_f32_16x16x32_bf16(a1, bat, sacc[1], 0, 0, 0);
        }
        if (l16 < 8) {
#pragma unroll
            for (int rt = 0; rt < 2; ++rt) {
#pragma unroll
                for (int reg = 0; reg < 4; ++reg) {
                    int node = n0 + wave * 32 + rt * 16 + quad * 4 + reg;
                    if (node < N_NODES)
                        sTab[((size_t)r * N_NODES + node) * 8 + l16] = sacc[rt][reg];
                }
            }
        }
    }

    {
        const ushort* rp = &wt[0][0];
        const size_t rbase = (size_t)r * N_NODES * DIM;
#pragma unroll
        for (int p = 0; p < 8; ++p) {
            int row = p * 16 + (tid >> 4);
            int chunk = tid & 15;
            int node = n0 + row;
            if (node < N_NODES) {
                uint4 v = *(const uint4*)(rp + row * 136 + chunk * 8);
                *(uint4*)(x_rel + rbase + (size_t)node * DIM + chunk * 8) = v;
            }
        }
    }
}

// C1: in-degree histogram
__global__ __launch_bounds__(256) void k_hist(
    const int* __restrict__ ei, uint* __restrict__ deg)
{
    int e = blockIdx.x * 256 + threadIdx.x;
    if (e >= N_EDGES) return;
    atomicAdd(&deg[ei[N_EDGES + e]], 1u);
}

// C2a: per-block exclusive scan + block sums
__global__ __launch_bounds__(256) void k_scan1(
    const uint* __restrict__ deg, uint* __restrict__ excl, uint* __restrict__ bsum)
{
    __shared__ uint tmp[256];
    int i = blockIdx.x * 256 + threadIdx.x;
    uint v = (i < N_NODES) ? deg[i] : 0u;
    tmp[threadIdx.x] = v;
    __syncthreads();
    for (int off = 1; off < 256; off <<= 1) {
        uint t = (threadIdx.x >= off) ? tmp[threadIdx.x - off] : 0u;
        __syncthreads();
        tmp[threadIdx.x] += t;
        __syncthreads();
    }
    if (i < N_NODES) excl[i] = tmp[threadIdx.x] - v;
    if (threadIdx.x == 255) bsum[blockIdx.x] = tmp[255];
}

// C2b: scan block sums (nblocks <= 512)
__global__ __launch_bounds__(512) void k_scan2(uint* __restrict__ bsum, int nblocks)
{
    __shared__ uint tmp[512];
    int t = threadIdx.x;
    uint v = (t < nblocks) ? bsum[t] : 0u;
    tmp[t] = v;
    __syncthreads();
    for (int off = 1; off < 512; off <<= 1) {
        uint tt = (t >= off) ? tmp[t - off] : 0u;
        __syncthreads();
        tmp[t] += tt;
        __syncthreads();
    }
    if (t < nblocks) bsum[t] = tmp[t] - v;   // exclusive
}

// C2c: start = excl + block offset; cursor = start
__global__ __launch_bounds__(256) void k_scan3(
    const uint* __restrict__ excl, const uint* __restrict__ bsum,
    uint* __restrict__ start, uint* __restrict__ cursor)
{
    int i = blockIdx.x * 256 + threadIdx.x;
    if (i >= N_NODES) return;
    uint s = excl[i] + bsum[blockIdx.x];
    start[i] = s;
    cursor[i] = s;
}

// C3: fill CSR: packed (src | rel<<27)
__global__ __launch_bounds__(256) void k_fill(
    const int* __restrict__ ei, const int* __restrict__ et,
    uint* __restrict__ cursor, uint* __restrict__ csrPack)
{
    int e = blockIdx.x * 256 + threadIdx.x;
    if (e >= N_EDGES) return;
    int s = ei[e];
    int d = ei[N_EDGES + e];
    int r = et[e];
    uint pos = atomicAdd(&cursor[d], 1u);
    csrPack[pos] = (uint)s | ((uint)r << 27);
}

// K4 v3: fully-fused gather. One wave per dst. The softmax denominator is a
// per-(rel,head) SCALAR, so it factors out of the message sum:
//   out = sum_r (1/sum_{e in r} y_e) * sum_{e in r} y_e * x_e
// Each lane computes y for ITS head (component-select, no shfl), accumulates
// 4 per-rel accumulator pairs + 4 per-rel denominators, rescales at the end.
// Edge loop unrolled 4x with clamped indices + zero-masked pads so 4 sTab +
// 4 x_rel loads are in flight at once (was 1 -> latency-bound at 23% HBM).
// fmaf(0,x,a)==a exactly, so pads don't perturb results.

#define EDGE_LOAD(J) \
    uint sx##J = pk##J & 0x07FFFFFFu; \
    uint re##J = pk##J >> 27; \
    size_t rb##J = (size_t)re##J * N_NODES + sx##J; \
    float4 aV##J = *(const float4*)(sTab + rb##J * 8); \
    uint u##J = x_rel_u[rb##J * 64 + lane];

#define EDGE_ACC(J, VLD) { \
    float ah = (h < 2) ? (h == 0 ? aV##J.x : aV##J.y) : (h == 2 ? aV##J.z : aV##J.w); \
    float bb = (re##J < 2) ? (re##J == 0 ? b0 : b1) : (re##J == 2 ? b2 : b3); \
    float y = __expf(lrelu(ah + bb)); \
    y = (VLD) ? y : 0.f; \
    float xlo = lo2f(u##J), xhi = hi2f(u##J); \
    float m0 = (re##J == 0) ? y : 0.f; \
    float m1 = (re##J == 1) ? y : 0.f; \
    float m2 = (re##J == 2) ? y : 0.f; \
    float m3 = (re##J == 3) ? y : 0.f; \
    ds0 += m0; ds1 += m1; ds2 += m2; ds3 += m3; \
    a0l = fmaf(m0, xlo, a0l); a0h = fmaf(m0, xhi, a0h); \
    a1l = fmaf(m1, xlo, a1l); a1h = fmaf(m1, xhi, a1h); \
    a2l = fmaf(m2, xlo, a2l); a2h = fmaf(m2, xhi, a2h); \
    a3l = fmaf(m3, xlo, a3l); a3h = fmaf(m3, xhi, a3h); \
}

__global__ __launch_bounds__(256) void k_gather3(
    const uint* __restrict__ start, const uint* __restrict__ deg,
    const uint* __restrict__ csrPack, const float* __restrict__ sTab,
    const uint* __restrict__ x_rel_u, float* __restrict__ out)
{
    const int wv = threadIdx.x >> 6;
    const int dst = blockIdx.x * 4 + wv;
    if (dst >= N_NODES) return;
    const int lane = threadIdx.x & 63;
    const int h = lane >> 4;

    const uint st = start[dst];
    const uint dg = deg[dst];

    // dst-part of the logit per rel, pre-selected for this lane's head
    float4 q0 = *(const float4*)(sTab + ((size_t)0 * N_NODES + dst) * 8 + 4);
    float4 q1 = *(const float4*)(sTab + ((size_t)1 * N_NODES + dst) * 8 + 4);
    float4 q2 = *(const float4*)(sTab + ((size_t)2 * N_NODES + dst) * 8 + 4);
    float4 q3 = *(const float4*)(sTab + ((size_t)3 * N_NODES + dst) * 8 + 4);
    float b0 = (h < 2) ? (h == 0 ? q0.x : q0.y) : (h == 2 ? q0.z : q0.w);
    float b1 = (h < 2) ? (h == 0 ? q1.x : q1.y) : (h == 2 ? q1.z : q1.w);
    float b2 = (h < 2) ? (h == 0 ? q2.x : q2.y) : (h == 2 ? q2.z : q2.w);
    float b3 = (h < 2) ? (h == 0 ? q3.x : q3.y) : (h == 2 ? q3.z : q3.w);

    float a0l = 0.f, a0h = 0.f, a1l = 0.f, a1h = 0.f;
    float a2l = 0.f, a2h = 0.f, a3l = 0.f, a3h = 0.f;
    float ds0 = 0.f, ds1 = 0.f, ds2 = 0.f, ds3 = 0.f;

    if (dg != 0u) {
        const uint last = st + dg - 1u;
        for (uint e0 = 0; e0 < dg; e0 += 4) {
            uint i0 = st + e0;
            uint i1 = (i0 + 1u <= last) ? i0 + 1u : last;
            uint i2 = (i0 + 2u <= last) ? i0 + 2u : last;
            uint i3 = (i0 + 3u <= last) ? i0 + 3u : last;
            uint pk0 = csrPack[i0];
            uint pk1 = csrPack[i1];
            uint pk2 = csrPack[i2];
            uint pk3 = csrPack[i3];
            EDGE_LOAD(0) EDGE_LOAD(1) EDGE_LOAD(2) EDGE_LOAD(3)
            EDGE_ACC(0, 1)
            EDGE_ACC(1, e0 + 1u < dg)
            EDGE_ACC(2, e0 + 2u < dg)
            EDGE_ACC(3, e0 + 3u < dg)
        }
    }

    // rels with no edges: ds==0 exactly (exp>0 always) -> rs=0 avoids 0*inf
    float rs0 = (ds0 > 0.f) ? 1.f / ds0 : 0.f;
    float rs1 = (ds1 > 0.f) ? 1.f / ds1 : 0.f;
    float rs2 = (ds2 > 0.f) ? 1.f / ds2 : 0.f;
    float rs3 = (ds3 > 0.f) ? 1.f / ds3 : 0.f;

    float2 o;
    o.x = a0l * rs0 + a1l * rs1 + a2l * rs2 + a3l * rs3;
    o.y = a0h * rs0 + a1h * rs1 + a2h * rs2 + a3h * rs3;
    *(float2*)(out + (size_t)dst * DIM + lane * 2) = o;
}

extern "C" void kernel_launch(void* const* d_in, const int* in_sizes, int n_in,
                              void* d_out, int out_size, void* d_ws, size_t ws_size,
                              hipStream_t stream) {
    const void* x    = d_in[0];
    const int*  ei   = (const int*)d_in[1];
    const int*  et   = (const int*)d_in[2];
    const void* W    = d_in[3];
    const void* attn = d_in[4];
    float* out = (float*)d_out;

    char* ws = (char*)d_ws;
    int*    flags   = (int*)(ws + 0);               // 256 B
    int*    eic     = (int*)(ws + 256);             // 4,800,000
    int*    etc_    = (int*)(ws + 4800256);         // 2,400,000
    float*  sTab    = (float*)(ws + 7200256);       // 12,800,000
    ushort* x_rel   = (ushort*)(ws + 20000256);     // 102,400,000
    uint*   deg     = (uint*)(ws + 122400256);      // 400,000
    uint*   excl    = (uint*)(ws + 122800256);      // 400,000
    uint*   bsum    = (uint*)(ws + 123200256);      // 2,048
    uint*   startA  = (uint*)(ws + 123202304);      // 400,000
    uint*   cursor  = (uint*)(ws + 123602304);      // 400,000
    uint*   csrPack = (uint*)(ws + 124002304);      // 2,400,000
    ushort* x_bf    = (ushort*)(ws + 126402304);    // 25,600,000
    // total 152,002,304 B
    // Aliases (stream-ordered disjoint lifetimes):
    //  Wt_g/at_g alias excl/startA (dead until k_scan1/k_scan3 write them).
    ushort* Wt_g    = (ushort*)(ws + 122800256);    // 139,264 (aliases excl)
    ushort* at_g    = (ushort*)(ws + 123202304);    // 17,408  (aliases startA)

    const int NBLK = (N_NODES + 255) / 256;   // 391

    hipMemsetAsync(deg, 0, 400000, stream);

    k_detect<<<1, 256, 0, stream>>>((const ushort*)x, (const ushort*)W,
                                    (const ushort*)attn, ei, et, flags);
    k_prep_w<<<N_REL, 256, 0, stream>>>(W, attn, flags, Wt_g, at_g);
    k_canon_i<<<(2 * N_EDGES / 4 + 255) / 256, 256, 0, stream>>>(ei, eic, 2 * N_EDGES, flags, 3);
    k_canon_i<<<(N_EDGES / 4 + 255) / 256, 256, 0, stream>>>(et, etc_, N_EDGES, flags, 4);
    k_cvt_x<<<(N_NODES * DIM / 8 + 255) / 256, 256, 0, stream>>>(x, flags, x_bf);

    k_gemm_mfma<<<((N_NODES + 127) / 128) * N_REL, 256, 0, stream>>>(x_bf, Wt_g, at_g,
                                                                     x_rel, sTab);

    k_hist<<<(N_EDGES + 255) / 256, 256, 0, stream>>>(eic, deg);
    k_scan1<<<NBLK, 256, 0, stream>>>(deg, excl, bsum);
    k_scan2<<<1, 512, 0, stream>>>(bsum, NBLK);
    k_scan3<<<NBLK, 256, 0, stream>>>(excl, bsum, startA, cursor);
    k_fill<<<(N_EDGES + 255) / 256, 256, 0, stream>>>(eic, etc_, cursor, csrPack);
    k_gather3<<<(N_NODES + 3) / 4, 256, 0, stream>>>(startA, deg, csrPack, sTab,
                                                     (const uint*)x_rel, out);
}